// Round 1
// baseline (67385.657 us; speedup 1.0000x reference)
//
#include <hip/hip_runtime.h>
#include <math.h>

#define ALPHA 0.01f
#define EPSF  1e-5f
#define NPRED 2048
#define MTARG 256
#define NT    256
#define CPT   (NPRED / NT)   // 8 columns per thread
#define NW    (NT / 64)      // 4 waves

__launch_bounds__(NT, 1)
__global__ void lap_loss_kernel(const float* __restrict__ pred,
                                const float* __restrict__ label,
                                float* __restrict__ out) {
  // SoA column data (predictions), everything LDS-resident
  __shared__ float s_ix[NPRED], s_iy[NPRED], s_iz[NPRED], s_iw[NPRED];
  __shared__ float s_sv[NPRED];        // (alpha*|inp|^2 + lca - lc) - v[j]  (dual folded in)
  __shared__ float s_short[NPRED];     // shortest path distances
  __shared__ short s_row4col[NPRED];   // -1 = unmatched
  __shared__ unsigned char s_path[NPRED];
  __shared__ unsigned char s_SC[NPRED];
  __shared__ unsigned char s_SR[MTARG];
  __shared__ float4 s_m2t[MTARG];      // -2*alpha*targ
  __shared__ float s_rc[MTARG];        // alpha*|targ|^2
  __shared__ float s_u[MTARG];
  __shared__ short s_col4row[MTARG];
  __shared__ float s_redv[NW];
  __shared__ int   s_redj[NW];
  __shared__ float s_scr[NW];
  __shared__ float s_sumlca;
  __shared__ int   s_i, s_sink;
  __shared__ float s_minval;

  const int tid = threadIdx.x;
  const float* pbase = pred  + (size_t)15 * NPRED * 5;
  const float* lbase = label + (size_t)15 * MTARG * 4;

  // ---- setup: columns (predictions) ----
  float lca_acc = 0.0f;
#pragma unroll
  for (int k = 0; k < CPT; ++k) {
    const int j = tid + k * NT;
    const float* p = pbase + j * 5;
    const float x = p[0], y = p[1], z = p[2], w = p[3], c = p[4];
    const float lc  = logf(c + EPSF);
    const float lca = logf(1.0f - c + EPSF);
    s_ix[j] = x; s_iy[j] = y; s_iz[j] = z; s_iw[j] = w;
    s_sv[j] = ALPHA * (x*x + y*y + z*z + w*w) + (lca - lc);   // v[j] = 0 initially
    s_row4col[j] = -1;
    lca_acc += lca;
  }
  // ---- setup: rows (targets) ----
  {
    const float* t = lbase + tid * 4;
    const float tx = t[0], ty = t[1], tz = t[2], tw = t[3];
    s_m2t[tid] = make_float4(-2.0f*ALPHA*tx, -2.0f*ALPHA*ty, -2.0f*ALPHA*tz, -2.0f*ALPHA*tw);
    s_rc[tid]  = ALPHA * (tx*tx + ty*ty + tz*tz + tw*tw);
    s_u[tid] = 0.0f;
    s_col4row[tid] = -1;
  }
  // sum of log(1-c+eps) over ALL predictions (deterministic tree reduce)
#pragma unroll
  for (int off = 32; off > 0; off >>= 1) lca_acc += __shfl_down(lca_acc, off);
  if ((tid & 63) == 0) s_scr[tid >> 6] = lca_acc;
  __syncthreads();
  if (tid == 0) {
    float s = 0.0f;
    for (int w2 = 0; w2 < NW; ++w2) s += s_scr[w2];
    s_sumlca = s;
  }

  // ---- main loop: one augmentation per target row ----
  for (int cur = 0; cur < MTARG; ++cur) {
#pragma unroll
    for (int k = 0; k < CPT; ++k) {
      const int j = tid + k * NT;
      s_short[j] = INFINITY;
      s_SC[j] = 0;
    }
    s_SR[tid] = (tid == cur) ? (unsigned char)1 : (unsigned char)0;
    if (tid == 0) { s_i = cur; s_sink = -1; s_minval = 0.0f; }
    __syncthreads();

    for (;;) {
      if (s_sink >= 0) break;                 // uniform: read after barrier
      const int i = s_i;
      const float4 m2 = s_m2t[i];
      const float base = s_rc[i] + s_minval - s_u[i];
      float bestv = INFINITY;
      int   bestj = 0x7FFFFFFF;
#pragma unroll
      for (int k = 0; k < CPT; ++k) {
        const int j = tid + k * NT;
        if (!s_SC[j]) {
          const float d = base + s_sv[j]
                        + m2.x * s_ix[j] + m2.y * s_iy[j]
                        + m2.z * s_iz[j] + m2.w * s_iw[j];
          float sj = s_short[j];
          if (d < sj) { s_short[j] = d; s_path[j] = (unsigned char)i; sj = d; }
          if (sj < bestv)                 { bestv = sj; bestj = j; }
          else if (sj == bestv && j < bestj) { bestj = j; }
        }
      }
      // (value, index)-min reduce: wave shuffle then cross-wave
#pragma unroll
      for (int off = 32; off > 0; off >>= 1) {
        const float ov = __shfl_down(bestv, off);
        const int   oj = __shfl_down(bestj, off);
        if (ov < bestv || (ov == bestv && oj < bestj)) { bestv = ov; bestj = oj; }
      }
      if ((tid & 63) == 0) { s_redv[tid >> 6] = bestv; s_redj[tid >> 6] = bestj; }
      __syncthreads();
      if (tid == 0) {
        float bv = s_redv[0]; int bj = s_redj[0];
        for (int w2 = 1; w2 < NW; ++w2) {
          const float ov = s_redv[w2]; const int oj = s_redj[w2];
          if (ov < bv || (ov == bv && oj < bj)) { bv = ov; bj = oj; }
        }
        s_minval = bv;
        s_SC[bj] = 1;
        const int r = s_row4col[bj];
        if (r < 0) s_sink = bj;
        else { s_i = r; s_SR[r] = 1; }
      }
      __syncthreads();
    }

    // dual updates (on pre-augmentation state)
    const float mv = s_minval;
    const int   snk = s_sink;
    if (s_SR[tid]) {
      s_u[tid] += (tid == cur) ? mv : (mv - s_short[s_col4row[tid]]);
    }
#pragma unroll
    for (int k = 0; k < CPT; ++k) {
      const int j = tid + k * NT;
      if (s_SC[j]) s_sv[j] += mv - s_short[j];   // v[j] -= (mv - shortest[j])
    }
    __syncthreads();
    // augment along alternating path (serial pointer chase)
    if (tid == 0) {
      int j = snk;
      for (;;) {
        const int r = s_path[j];
        s_row4col[j] = (short)r;
        const short tmp = s_col4row[r];
        s_col4row[r] = (short)j;
        if (r == cur) break;
        j = tmp;
      }
    }
    __syncthreads();
  }

  // ---- loss: sum matched costs (recomputed from global) minus sum_lca ----
  float loc = 0.0f;
  {
    const int j = (int)s_col4row[tid];
    const float* p = pbase + j * 5;
    const float x = p[0], y = p[1], z = p[2], w = p[3], c = p[4];
    const float lc  = logf(c + EPSF);
    const float lca = logf(1.0f - c + EPSF);
    const float* t = lbase + tid * 4;
    const float dx = x - t[0], dy = y - t[1], dz = z - t[2], dw = w - t[3];
    loc = ALPHA * (dx*dx + dy*dy + dz*dz + dw*dw) - lc + lca;
  }
#pragma unroll
  for (int off = 32; off > 0; off >>= 1) loc += __shfl_down(loc, off);
  __syncthreads();
  if ((tid & 63) == 0) s_scr[tid >> 6] = loc;
  __syncthreads();
  if (tid == 0) {
    float s = 0.0f;
    for (int w2 = 0; w2 < NW; ++w2) s += s_scr[w2];
    out[0] = s - s_sumlca;
  }
}

extern "C" void kernel_launch(void* const* d_in, const int* in_sizes, int n_in,
                              void* d_out, int out_size, void* d_ws, size_t ws_size,
                              hipStream_t stream) {
  const float* pred  = (const float*)d_in[0];
  const float* label = (const float*)d_in[1];
  float* out = (float*)d_out;
  hipLaunchKernelGGL(lap_loss_kernel, dim3(1), dim3(NT), 0, stream,
                     pred, label, out);
}

// Round 2
// 3632.430 us; speedup vs baseline: 18.5511x; 18.5511x over previous
//
#include <hip/hip_runtime.h>
#include <math.h>

#define ALPHA 0.01f
#define EPSF  1e-5f
#define NPRED 2048
#define MTARG 256
#define NT    256
#define CPT   8            // NPRED / NT
#define KMAX  512
#define SPT   2            // KMAX / NT
#define NW    4            // waves per block
#define MARGIN 0.041f      // alpha*4 (max geometric term) + fp safety
#define BIGF  1e30f

__launch_bounds__(NT, 1)
__global__ void lap_loss_kernel(const float* __restrict__ pred,
                                const float* __restrict__ label,
                                float* __restrict__ out) {
  // full column stats
  __shared__ __align__(16) float s_all[NPRED];   // s_j = log(1-c+e) - log(c+e)
  // compacted kept columns (slots 0..K-1, K<=KMAX)
  __shared__ float4 s_k4[KMAX];      // pred coords
  __shared__ float  s_sv[KMAX];      // alpha*|p|^2 (pristine)
  __shared__ float  s_scol[KMAX];    // s_j (pristine)
  __shared__ float  s_v[KMAX];       // dual v
  __shared__ float  s_short[KMAX];
  __shared__ short  s_row4col[KMAX];
  __shared__ short  s_path[KMAX];
  __shared__ unsigned char s_SC[KMAX];
  // rows: 0..255 real (targets), 256..K-1 dummy
  __shared__ float  s_u[KMAX];
  __shared__ unsigned char s_SR[KMAX];
  __shared__ short  s_col4row[KMAX];
  __shared__ float4 s_m2t[MTARG];    // -2*alpha*targ
  __shared__ float  s_rc[MTARG];     // alpha*|targ|^2
  __shared__ short  s_amin[MTARG];
  __shared__ short  s_todo[KMAX];
  // reduction scratch / scalars
  __shared__ float s_redv[NW];
  __shared__ int   s_redj[NW];
  __shared__ float s_scr[NW];
  __shared__ float s_pivot, s_smax, s_sumkept, s_sumlca;
  __shared__ int   s_K, s_T, s_i, s_sink;
  __shared__ float s_minval;

  const int tid = threadIdx.x;
  const float* pbase = pred  + (size_t)15 * NPRED * 5;
  const float* lbase = label + (size_t)15 * MTARG * 4;

  // ---------- phase 0: per-column s_j, sum of lca over all 2048 ----------
  float mys[CPT];
  float lca_acc = 0.0f;
#pragma unroll
  for (int k = 0; k < CPT; ++k) {
    const int j = tid + k * NT;
    const float c = pbase[j * 5 + 4];
    const float lc  = logf(c + EPSF);
    const float lca = logf(1.0f - c + EPSF);
    const float s = lca - lc;
    mys[k] = s;
    s_all[j] = s;
    lca_acc += lca;
  }
#pragma unroll
  for (int off = 32; off > 0; off >>= 1) lca_acc += __shfl_down(lca_acc, off);
  if ((tid & 63) == 0) s_scr[tid >> 6] = lca_acc;
  if (tid == 0) s_K = 0;
  __syncthreads();
  if (tid == 0) {
    float s = 0.0f;
    for (int w = 0; w < NW; ++w) s += s_scr[w];
    s_sumlca = s;
  }

  // ---------- phase 1: exact ranks by counting (ties by index) ----------
  int myrank[CPT];
#pragma unroll
  for (int k = 0; k < CPT; ++k) myrank[k] = 0;
  {
    const float4* s4 = (const float4*)s_all;
    for (int kk4 = 0; kk4 < NPRED / 4; ++kk4) {
      const float4 sq = s4[kk4];
      const int kb = kk4 * 4;
#pragma unroll
      for (int q = 0; q < 4; ++q) {
        const float sk = (q == 0) ? sq.x : (q == 1) ? sq.y : (q == 2) ? sq.z : sq.w;
        const int kk = kb + q;
#pragma unroll
        for (int k = 0; k < CPT; ++k) {
          const int j = tid + k * NT;
          myrank[k] += (sk < mys[k] || (sk == mys[k] && kk < j)) ? 1 : 0;
        }
      }
    }
  }
#pragma unroll
  for (int k = 0; k < CPT; ++k)
    if (myrank[k] == MTARG - 1) s_pivot = mys[k];   // s_(255), exactly one writer
  __syncthreads();

  // ---------- phase 2: keep + compact (slot = rank), reduce K/sum/max ----------
  {
    const float keepThr = s_pivot + MARGIN;
    int   cnt = 0;
    float sumk = 0.0f;
    float maxk = -BIGF;
#pragma unroll
    for (int k = 0; k < CPT; ++k) {
      const int j = tid + k * NT;
      const float s = mys[k];
      if (s <= keepThr && myrank[k] < KMAX) {
        const int slot = myrank[k];
        const float* p = pbase + j * 5;
        const float x = p[0], y = p[1], z = p[2], w = p[3];
        s_k4[slot]   = make_float4(x, y, z, w);
        s_sv[slot]   = ALPHA * (x*x + y*y + z*z + w*w);
        s_scol[slot] = s;
        s_v[slot]    = 0.0f;
        s_row4col[slot] = -1;
        cnt++; sumk += s; if (s > maxk) maxk = s;
      }
    }
#pragma unroll
    for (int off = 32; off > 0; off >>= 1) {
      cnt  += __shfl_down(cnt, off);
      sumk += __shfl_down(sumk, off);
      const float om = __shfl_down(maxk, off);
      if (om > maxk) maxk = om;
    }
    if ((tid & 63) == 0) { s_redj[tid >> 6] = cnt; s_scr[tid >> 6] = sumk; s_redv[tid >> 6] = maxk; }
  }
  // ---------- phase 3: rows + init ----------
  {
    const float* t = lbase + tid * 4;
    const float tx = t[0], ty = t[1], tz = t[2], tw = t[3];
    s_m2t[tid] = make_float4(-2.0f*ALPHA*tx, -2.0f*ALPHA*ty, -2.0f*ALPHA*tz, -2.0f*ALPHA*tw);
    s_rc[tid]  = ALPHA * (tx*tx + ty*ty + tz*tz + tw*tw);
  }
#pragma unroll
  for (int k = 0; k < SPT; ++k) {
    const int r = tid + k * NT;
    s_u[r] = 0.0f;
    s_col4row[r] = -1;
  }
  __syncthreads();
  if (tid == 0) {
    int K = 0; float sumk = 0.0f, maxk = -BIGF;
    for (int w = 0; w < NW; ++w) {
      K += s_redj[w]; sumk += s_scr[w];
      if (s_redv[w] > maxk) maxk = s_redv[w];
    }
    s_K = K; s_sumkept = sumk; s_smax = maxk;
  }
  __syncthreads();
  const int   K    = s_K;
  const float smax = s_smax;

  // ---------- phase 4: greedy row reduction (real rows) ----------
  {
    const float4 m2 = s_m2t[tid];
    const float  rc = s_rc[tid];
    float best = BIGF; int bj = 0;
    for (int slot = 0; slot < K; ++slot) {
      const float4 k4 = s_k4[slot];
      const float d = rc + s_sv[slot]
                    + m2.x*k4.x + m2.y*k4.y + m2.z*k4.z + m2.w*k4.w;
      if (d < best) { best = d; bj = slot; }
    }
    s_u[tid] = best;
    s_amin[tid] = (short)bj;
  }
  __syncthreads();
  if (tid == 0) {
    int T = 0;
    for (int i = 0; i < MTARG; ++i) {
      const int j = (int)s_amin[i];
      if (s_row4col[j] < 0) { s_row4col[j] = (short)i; s_col4row[i] = (short)j; }
      else s_todo[T++] = (short)i;
    }
    for (int d = MTARG; d < K; ++d) s_todo[T++] = (short)d;  // dummy rows (u=0 is their true min)
    s_T = T;
  }
  __syncthreads();
  const int T = s_T;

  // ---------- phase 5: SAP augmentations ----------
  for (int t = 0; t < T; ++t) {
    const int cur = (int)s_todo[t];
#pragma unroll
    for (int k = 0; k < SPT; ++k) {
      const int slot = tid + k * NT;
      s_short[slot] = BIGF;
      s_SC[slot] = (slot >= K) ? 1 : 0;
      s_SR[slot] = (slot == cur) ? 1 : 0;
    }
    if (tid == 0) { s_i = cur; s_sink = -1; s_minval = 0.0f; }
    __syncthreads();

    for (int pop = 0; pop <= KMAX; ++pop) {
      if (s_sink >= 0) break;
      const int i = s_i;
      const bool geo = (i < MTARG);
      float4 m2; float base;
      if (geo) { m2 = s_m2t[i]; base = s_rc[i] + s_minval - s_u[i]; }
      else     { base = s_minval - s_u[i] + smax; }
      float bestv = BIGF; int bestj = 0x7FFFFFFF;
#pragma unroll
      for (int k = 0; k < SPT; ++k) {
        const int slot = tid + k * NT;
        if (!s_SC[slot]) {
          float d;
          if (geo) {
            const float4 k4 = s_k4[slot];
            d = base + s_sv[slot] - s_v[slot]
              + m2.x*k4.x + m2.y*k4.y + m2.z*k4.z + m2.w*k4.w;
          } else {
            d = base - s_scol[slot] - s_v[slot];
          }
          float sj = s_short[slot];
          if (d < sj) { s_short[slot] = d; s_path[slot] = (short)i; sj = d; }
          if (sj < bestv || (sj == bestv && slot < bestj)) { bestv = sj; bestj = slot; }
        }
      }
#pragma unroll
      for (int off = 32; off > 0; off >>= 1) {
        const float ov = __shfl_down(bestv, off);
        const int   oj = __shfl_down(bestj, off);
        if (ov < bestv || (ov == bestv && oj < bestj)) { bestv = ov; bestj = oj; }
      }
      if ((tid & 63) == 0) { s_redv[tid >> 6] = bestv; s_redj[tid >> 6] = bestj; }
      __syncthreads();
      if (tid == 0) {
        float bv = s_redv[0]; int bj = s_redj[0];
        for (int w = 1; w < NW; ++w) {
          const float ov = s_redv[w]; const int oj = s_redj[w];
          if (ov < bv || (ov == bv && oj < bj)) { bv = ov; bj = oj; }
        }
        if (bj >= KMAX) {           // safety: should never happen
          s_sink = 0;
        } else {
          s_minval = bv;
          s_SC[bj] = 1;
          const int r = (int)s_row4col[bj];
          if (r < 0) s_sink = bj;
          else { s_i = r; s_SR[r] = 1; }
        }
      }
      __syncthreads();
    }

    // dual updates (pre-augmentation state)
    const float mv = s_minval;
    const int   snk = s_sink;
#pragma unroll
    for (int k = 0; k < SPT; ++k) {
      const int r = tid + k * NT;
      if (r < K) {
        if (s_SR[r]) s_u[r] += (r == cur) ? mv : (mv - s_short[(int)s_col4row[r]]);
        if (s_SC[r]) s_v[r] -= (mv - s_short[r]);
      }
    }
    __syncthreads();
    // augment (serial pointer chase)
    if (tid == 0) {
      int j = snk;
      for (;;) {
        const int r = (int)s_path[j];
        s_row4col[j] = (short)r;
        const short tmp = s_col4row[r];
        s_col4row[r] = (short)j;
        if (r == cur) break;
        j = (int)tmp;
      }
    }
    __syncthreads();
  }

  // ---------- phase 6: value = LAPsum + sum_kept(s) - (K-256)*smax - sum_lca ----------
  float acc = 0.0f;
#pragma unroll
  for (int k = 0; k < SPT; ++k) {
    const int r = tid + k * NT;
    if (r < K) {
      const int slot = (int)s_col4row[r];
      if (r < MTARG) {
        const float4 k4 = s_k4[slot];
        const float4 m2 = s_m2t[r];
        acc += s_rc[r] + s_sv[slot]
             + m2.x*k4.x + m2.y*k4.y + m2.z*k4.z + m2.w*k4.w;
      } else {
        acc += smax - s_scol[slot];
      }
    }
  }
#pragma unroll
  for (int off = 32; off > 0; off >>= 1) acc += __shfl_down(acc, off);
  __syncthreads();
  if ((tid & 63) == 0) s_scr[tid >> 6] = acc;
  __syncthreads();
  if (tid == 0) {
    float s = 0.0f;
    for (int w = 0; w < NW; ++w) s += s_scr[w];
    out[0] = s + s_sumkept - (float)(K - MTARG) * smax - s_sumlca;
  }
}

extern "C" void kernel_launch(void* const* d_in, const int* in_sizes, int n_in,
                              void* d_out, int out_size, void* d_ws, size_t ws_size,
                              hipStream_t stream) {
  const float* pred  = (const float*)d_in[0];
  const float* label = (const float*)d_in[1];
  float* out = (float*)d_out;
  hipLaunchKernelGGL(lap_loss_kernel, dim3(1), dim3(NT), 0, stream,
                     pred, label, out);
}

// Round 3
// 3134.176 us; speedup vs baseline: 21.5003x; 1.1590x over previous
//
#include <hip/hip_runtime.h>
#include <math.h>

#define ALPHA 0.01f
#define EPSF  1e-5f
#define NPRED 2048
#define MTARG 256
#define NT    256
#define CPT   8            // NPRED / NT
#define KMAX  512
#define SPT   2            // KMAX / NT
#define SPL   8            // KMAX / 64 slots per lane (wave-0 SAP)
#define NW    4
#define MARGIN 0.041f
#define BIGF  1e30f

__launch_bounds__(NT, 1)
__global__ void lap_loss_kernel(const float* __restrict__ pred,
                                const float* __restrict__ label,
                                float* __restrict__ out) {
  __shared__ __align__(16) float s_all[NPRED];
  __shared__ float4 s_k4[KMAX];
  __shared__ float  s_sv[KMAX];
  __shared__ float  s_scol[KMAX];
  __shared__ float  s_v[KMAX];
  __shared__ short  s_row4col[KMAX];
  __shared__ short  s_argr[KMAX];
  __shared__ float  s_u[KMAX];
  __shared__ short  s_col4row[KMAX];
  __shared__ float4 s_m2t[MTARG];
  __shared__ float  s_rc[MTARG];
  __shared__ short  s_amin[MTARG];
  __shared__ short  s_todo[KMAX];
  __shared__ float s_redv[NW];
  __shared__ int   s_redj[NW];
  __shared__ float s_scr[NW];
  __shared__ float s_pivot, s_smax, s_sumkept, s_sumlca;
  __shared__ int   s_K, s_T;

  const int tid = threadIdx.x;
  const float* pbase = pred  + (size_t)15 * NPRED * 5;
  const float* lbase = label + (size_t)15 * MTARG * 4;

  // ---------- phase 0: per-column s_j, sum lca ----------
  float mys[CPT];
  float lca_acc = 0.0f;
#pragma unroll
  for (int k = 0; k < CPT; ++k) {
    const int j = tid + k * NT;
    const float c = pbase[j * 5 + 4];
    const float lc  = logf(c + EPSF);
    const float lca = logf(1.0f - c + EPSF);
    const float s = lca - lc;
    mys[k] = s;
    s_all[j] = s;
    lca_acc += lca;
  }
#pragma unroll
  for (int off = 32; off > 0; off >>= 1) lca_acc += __shfl_down(lca_acc, off);
  if ((tid & 63) == 0) s_scr[tid >> 6] = lca_acc;
  __syncthreads();
  if (tid == 0) {
    float s = 0.0f;
    for (int w = 0; w < NW; ++w) s += s_scr[w];
    s_sumlca = s;
  }

  // ---------- phase 1: exact ranks ----------
  int myrank[CPT];
#pragma unroll
  for (int k = 0; k < CPT; ++k) myrank[k] = 0;
  {
    const float4* s4 = (const float4*)s_all;
    for (int kk4 = 0; kk4 < NPRED / 4; ++kk4) {
      const float4 sq = s4[kk4];
      const int kb = kk4 * 4;
#pragma unroll
      for (int q = 0; q < 4; ++q) {
        const float sk = (q == 0) ? sq.x : (q == 1) ? sq.y : (q == 2) ? sq.z : sq.w;
        const int kk = kb + q;
#pragma unroll
        for (int k = 0; k < CPT; ++k) {
          const int j = tid + k * NT;
          myrank[k] += (sk < mys[k] || (sk == mys[k] && kk < j)) ? 1 : 0;
        }
      }
    }
  }
#pragma unroll
  for (int k = 0; k < CPT; ++k)
    if (myrank[k] == MTARG - 1) s_pivot = mys[k];
  __syncthreads();

  // ---------- phase 2: compact kept columns (slot = rank) ----------
  {
    const float keepThr = s_pivot + MARGIN;
    int   cnt = 0;
    float sumk = 0.0f;
    float maxk = -BIGF;
#pragma unroll
    for (int k = 0; k < CPT; ++k) {
      const int j = tid + k * NT;
      const float s = mys[k];
      if (s <= keepThr && myrank[k] < KMAX) {
        const int slot = myrank[k];
        const float* p = pbase + j * 5;
        const float x = p[0], y = p[1], z = p[2], w = p[3];
        s_k4[slot]   = make_float4(x, y, z, w);
        s_sv[slot]   = ALPHA * (x*x + y*y + z*z + w*w);
        s_scol[slot] = s;
        s_row4col[slot] = -1;
        cnt++; sumk += s; if (s > maxk) maxk = s;
      }
    }
#pragma unroll
    for (int off = 32; off > 0; off >>= 1) {
      cnt  += __shfl_down(cnt, off);
      sumk += __shfl_down(sumk, off);
      const float om = __shfl_down(maxk, off);
      if (om > maxk) maxk = om;
    }
    if ((tid & 63) == 0) { s_redj[tid >> 6] = cnt; s_scr[tid >> 6] = sumk; s_redv[tid >> 6] = maxk; }
  }
  // rows init
  {
    const float* t = lbase + tid * 4;
    const float tx = t[0], ty = t[1], tz = t[2], tw = t[3];
    s_m2t[tid] = make_float4(-2.0f*ALPHA*tx, -2.0f*ALPHA*ty, -2.0f*ALPHA*tz, -2.0f*ALPHA*tw);
    s_rc[tid]  = ALPHA * (tx*tx + ty*ty + tz*tz + tw*tw);
  }
#pragma unroll
  for (int k = 0; k < SPT; ++k) {
    const int r = tid + k * NT;
    s_u[r] = 0.0f;
    s_col4row[r] = -1;
  }
  __syncthreads();
  if (tid == 0) {
    int K = 0; float sumk = 0.0f, maxk = -BIGF;
    for (int w = 0; w < NW; ++w) {
      K += s_redj[w]; sumk += s_scr[w];
      if (s_redv[w] > maxk) maxk = s_redv[w];
    }
    s_K = K; s_sumkept = sumk; s_smax = maxk;
  }
  __syncthreads();
  const int   K    = s_K;
  const float smax = s_smax;

  // ---------- phase 4: row reduction (u = row minima) ----------
  {
    const float4 m2 = s_m2t[tid];
    const float  rc = s_rc[tid];
    float best = BIGF; int bj = 0;
    for (int slot = 0; slot < K; ++slot) {
      const float4 k4 = s_k4[slot];
      const float d = rc + s_sv[slot]
                    + m2.x*k4.x + m2.y*k4.y + m2.z*k4.z + m2.w*k4.w;
      if (d < best) { best = d; bj = slot; }
    }
    s_u[tid] = best;
    s_amin[tid] = (short)bj;
  }
  __syncthreads();

  // ---------- phase 4b: column reduction (v = col minima of reduced costs) ----------
#pragma unroll
  for (int k = 0; k < SPT; ++k) {
    const int slot = tid + k * NT;
    if (slot < K) {
      const float4 q = s_k4[slot];
      const float svv = s_sv[slot];
      float best = BIGF; int br = -1;
      for (int i = 0; i < MTARG; ++i) {
        const float4 m2 = s_m2t[i];
        const float d = s_rc[i] + svv - s_u[i]
                      + m2.x*q.x + m2.y*q.y + m2.z*q.z + m2.w*q.w;
        if (d < best) { best = d; br = i; }
      }
      const float dval = smax - s_scol[slot];   // dummy-row bound (u_dummy = 0)
      if (dval < best) { best = dval; br = -1; }
      s_v[slot] = best;
      s_argr[slot] = (short)br;
    } else {
      s_v[slot] = 0.0f;
      s_argr[slot] = -1;
    }
  }
  __syncthreads();

  // ---------- phase 4c: greedy tight matchings + todo list (serial) ----------
  if (tid == 0) {
    // row-argmin greedy (those columns have v == 0, pairs tight)
    for (int i = 0; i < MTARG; ++i) {
      const int j = (int)s_amin[i];
      if (s_row4col[j] < 0) { s_row4col[j] = (short)i; s_col4row[i] = (short)j; }
    }
    // column-argmin greedy (tight by construction of v)
    for (int j = 0; j < K; ++j) {
      if (s_row4col[j] < 0) {
        const int r = (int)s_argr[j];
        if (r >= 0 && s_col4row[r] < 0) { s_row4col[j] = (short)r; s_col4row[r] = (short)j; }
      }
    }
    int T = 0;
    for (int i = 0; i < MTARG; ++i) if (s_col4row[i] < 0) s_todo[T++] = (short)i;
    for (int d = MTARG; d < K; ++d) s_todo[T++] = (short)d;
    s_T = T;
  }
  __syncthreads();

  // ---------- phase 5: wave-0 barrier-free SAP ----------
  if (tid < 64) {
    const int lane = tid;
    // load per-slot state into registers (slot = lane + 64*k)
    float kxr[SPL], kyr[SPL], kzr[SPL], kwr[SPL];
    float svr[SPL], sclr[SPL], vr[SPL], shv[SPL];
    int   pth[SPL], r4cr[SPL];
    unsigned int invm = 0;
#pragma unroll
    for (int k = 0; k < SPL; ++k) {
      const int slot = lane + 64 * k;
      const float4 q = s_k4[slot];
      kxr[k] = q.x; kyr[k] = q.y; kzr[k] = q.z; kwr[k] = q.w;
      svr[k] = s_sv[slot]; sclr[k] = s_scol[slot]; vr[k] = s_v[slot];
      r4cr[k] = (int)s_row4col[slot];
      pth[k] = 0;
      if (slot >= K) invm |= (1u << k);
    }
    const int T = s_T;

    for (int t = 0; t < T; ++t) {
      const int cur = (int)s_todo[t];
      unsigned int scm = invm;
#pragma unroll
      for (int k = 0; k < SPL; ++k) shv[k] = BIGF;
      float minval = 0.0f;
      int i = cur;
      int sink = -1;

      for (int pop = 0; pop <= KMAX && sink < 0; ++pop) {
        const bool geo = (i < MTARG);
        const float ui = s_u[i];
        float4 m2 = make_float4(0.f, 0.f, 0.f, 0.f);
        float base;
        if (geo) { m2 = s_m2t[i]; base = s_rc[i] + minval - ui; }
        else     { base = minval - ui + smax; }

        float bestv = BIGF; int bestj = 0x7FFFFFFF;
#pragma unroll
        for (int k = 0; k < SPL; ++k) {
          if (!(scm & (1u << k))) {
            float d;
            if (geo) {
              d = base + svr[k] - vr[k]
                + m2.x*kxr[k] + m2.y*kyr[k] + m2.z*kzr[k] + m2.w*kwr[k];
            } else {
              d = base - sclr[k] - vr[k];
            }
            if (d < shv[k]) { shv[k] = d; pth[k] = i; }
            const float sj = shv[k];
            if (sj < bestv) { bestv = sj; bestj = lane + 64 * k; }
          }
        }
        // 64-lane (value,index) butterfly min-reduce
#pragma unroll
        for (int off = 1; off < 64; off <<= 1) {
          const float ov = __shfl_xor(bestv, off);
          const int   oj = __shfl_xor(bestj, off);
          if (ov < bestv || (ov == bestv && oj < bestj)) { bestv = ov; bestj = oj; }
        }
        if (bestj >= KMAX) break;   // safety (cannot happen: cols >= rows)
        minval = bestv;
        const int bl = bestj & 63, bk = bestj >> 6;
        if (lane == bl) {
#pragma unroll
          for (int k = 0; k < SPL; ++k) if (bk == k) scm |= (1u << k);
        }
        int rsel = r4cr[0];
#pragma unroll
        for (int k = 1; k < SPL; ++k) if (bk == k) rsel = r4cr[k];
        const int r = __shfl(rsel, bl);
        if (r < 0) sink = bestj;
        else       i = r;
      }

      // dual updates (pre-augmentation matching in r4cr)
      const float mv = minval;
#pragma unroll
      for (int k = 0; k < SPL; ++k) {
        const unsigned int bit = 1u << k;
        if ((scm & bit) && !(invm & bit)) {
          const float delta = mv - shv[k];
          vr[k] -= delta;
          const int r = r4cr[k];
          if (r >= 0) s_u[r] += delta;   // distinct r per (lane,slot): race-free
        }
      }
      if (lane == 0) s_u[cur] += mv;
      __threadfence_block();

      // augment: pointer chase (redundant on all lanes; lane 0 writes LDS)
      int j = sink;
      for (int st = 0; st <= KMAX; ++st) {
        const int bl = j & 63, bk = j >> 6;
        int psel = pth[0];
#pragma unroll
        for (int k = 1; k < SPL; ++k) if (bk == k) psel = pth[k];
        const int r = __shfl(psel, bl);
        if (lane == bl) {
#pragma unroll
          for (int k = 0; k < SPL; ++k) if (bk == k) r4cr[k] = r;
        }
        const int tmp = (int)s_col4row[r];
        if (lane == 0) s_col4row[r] = (short)j;
        if (r == cur) break;
        j = tmp;
      }
      __threadfence_block();
    }
  }
  __syncthreads();

  // ---------- phase 6: recompute matched costs, final value ----------
  float acc = 0.0f;
#pragma unroll
  for (int k = 0; k < SPT; ++k) {
    const int r = tid + k * NT;
    if (r < K) {
      const int slot = (int)s_col4row[r];
      if (r < MTARG) {
        const float4 k4 = s_k4[slot];
        const float4 m2 = s_m2t[r];
        acc += s_rc[r] + s_sv[slot]
             + m2.x*k4.x + m2.y*k4.y + m2.z*k4.z + m2.w*k4.w;
      } else {
        acc += smax - s_scol[slot];
      }
    }
  }
#pragma unroll
  for (int off = 32; off > 0; off >>= 1) acc += __shfl_down(acc, off);
  __syncthreads();
  if ((tid & 63) == 0) s_scr[tid >> 6] = acc;
  __syncthreads();
  if (tid == 0) {
    float s = 0.0f;
    for (int w = 0; w < NW; ++w) s += s_scr[w];
    out[0] = s + s_sumkept - (float)(K - MTARG) * smax - s_sumlca;
  }
}

extern "C" void kernel_launch(void* const* d_in, const int* in_sizes, int n_in,
                              void* d_out, int out_size, void* d_ws, size_t ws_size,
                              hipStream_t stream) {
  const float* pred  = (const float*)d_in[0];
  const float* label = (const float*)d_in[1];
  float* out = (float*)d_out;
  hipLaunchKernelGGL(lap_loss_kernel, dim3(1), dim3(NT), 0, stream,
                     pred, label, out);
}

// Round 4
// 885.063 us; speedup vs baseline: 76.1366x; 3.5412x over previous
//
#include <hip/hip_runtime.h>
#include <math.h>

#define ALPHA 0.01f
#define EPSF  1e-5f
#define NPRED 2048
#define MTARG 256
#define NT    256
#define CPT   8            // NPRED / NT
#define KMAX  512
#define SPT   2            // KMAX / NT
#define NW    4
#define MARGIN 0.041f      // alpha*4 (max geo term) + fp safety
#define BIGF  1e30f
#define EPSA  0.02f        // auction epsilon: gap <= 256*EPSA = 5.12 << 24.8
#define MAXSWEEP 4096

__launch_bounds__(NT, 1)
__global__ void lap_loss_kernel(const float* __restrict__ pred,
                                const float* __restrict__ label,
                                float* __restrict__ out) {
  __shared__ __align__(16) float s_all[NPRED];
  // kept columns (slot = rank), K <= KMAX
  __shared__ float4 s_k4[KMAX];      // pred coords
  __shared__ float  s_cc[KMAX];      // alpha*|p|^2 + s_j  (full column constant)
  __shared__ float  s_p[KMAX];       // auction price
  __shared__ short  s_row4col[KMAX]; // owner row, -1 free
  __shared__ short  s_argr[KMAX];
  __shared__ unsigned long long s_bid[KMAX];
  // rows (targets)
  __shared__ float  s_u[MTARG];
  __shared__ short  s_col4row[MTARG];
  __shared__ float4 s_m2t[MTARG];    // -2*alpha*targ
  __shared__ float  s_rc[MTARG];     // alpha*|targ|^2
  __shared__ short  s_amin[MTARG];
  // scratch
  __shared__ float s_redv[NW];
  __shared__ int   s_redj[NW];
  __shared__ float s_scr[NW];
  __shared__ float s_pivot, s_sumlca;
  __shared__ int   s_K, s_ucnt;

  const int tid = threadIdx.x;
  const float* pbase = pred  + (size_t)15 * NPRED * 5;
  const float* lbase = label + (size_t)15 * MTARG * 4;

  // ---------- phase 0: per-column s_j, sum lca over all 2048 ----------
  float mys[CPT];
  float lca_acc = 0.0f;
#pragma unroll
  for (int k = 0; k < CPT; ++k) {
    const int j = tid + k * NT;
    const float c = pbase[j * 5 + 4];
    const float lc  = logf(c + EPSF);
    const float lca = logf(1.0f - c + EPSF);
    mys[k] = lca - lc;
    s_all[j] = mys[k];
    lca_acc += lca;
  }
#pragma unroll
  for (int off = 32; off > 0; off >>= 1) lca_acc += __shfl_down(lca_acc, off);
  if ((tid & 63) == 0) s_scr[tid >> 6] = lca_acc;
  __syncthreads();
  if (tid == 0) {
    float s = 0.0f;
    for (int w = 0; w < NW; ++w) s += s_scr[w];
    s_sumlca = s;
  }

  // ---------- phase 1: exact ranks of s_j (ties by index) ----------
  int myrank[CPT];
#pragma unroll
  for (int k = 0; k < CPT; ++k) myrank[k] = 0;
  {
    const float4* s4 = (const float4*)s_all;
    for (int kk4 = 0; kk4 < NPRED / 4; ++kk4) {
      const float4 sq = s4[kk4];
      const int kb = kk4 * 4;
#pragma unroll
      for (int q = 0; q < 4; ++q) {
        const float sk = (q == 0) ? sq.x : (q == 1) ? sq.y : (q == 2) ? sq.z : sq.w;
        const int kk = kb + q;
#pragma unroll
        for (int k = 0; k < CPT; ++k) {
          const int j = tid + k * NT;
          myrank[k] += (sk < mys[k] || (sk == mys[k] && kk < j)) ? 1 : 0;
        }
      }
    }
  }
#pragma unroll
  for (int k = 0; k < CPT; ++k)
    if (myrank[k] == MTARG - 1) s_pivot = mys[k];
  __syncthreads();

  // ---------- phase 2: compact kept columns (slot = rank) ----------
  {
    const float keepThr = s_pivot + MARGIN;
    int cnt = 0;
#pragma unroll
    for (int k = 0; k < CPT; ++k) {
      const int j = tid + k * NT;
      if (mys[k] <= keepThr && myrank[k] < KMAX) {
        const int slot = myrank[k];
        const float* p = pbase + j * 5;
        const float x = p[0], y = p[1], z = p[2], w = p[3];
        s_k4[slot]   = make_float4(x, y, z, w);
        s_cc[slot]   = ALPHA * (x*x + y*y + z*z + w*w) + mys[k];
        s_row4col[slot] = -1;
        cnt++;
      }
    }
#pragma unroll
    for (int off = 32; off > 0; off >>= 1) cnt += __shfl_down(cnt, off);
    if ((tid & 63) == 0) s_redj[tid >> 6] = cnt;
  }
  // rows init
  {
    const float* t = lbase + tid * 4;
    const float tx = t[0], ty = t[1], tz = t[2], tw = t[3];
    s_m2t[tid] = make_float4(-2.0f*ALPHA*tx, -2.0f*ALPHA*ty, -2.0f*ALPHA*tz, -2.0f*ALPHA*tw);
    s_rc[tid]  = ALPHA * (tx*tx + ty*ty + tz*tz + tw*tw);
    s_col4row[tid] = -1;
  }
  __syncthreads();
  if (tid == 0) {
    int K = 0;
    for (int w = 0; w < NW; ++w) K += s_redj[w];
    s_K = K;
  }
  __syncthreads();
  const int K = s_K;

  // ---------- phase 4: row reduction on FULL cost ----------
  {
    const float4 m2 = s_m2t[tid];
    const float  rc = s_rc[tid];
    float best = BIGF; int bj = 0;
    for (int slot = 0; slot < K; ++slot) {
      const float4 q = s_k4[slot];
      const float d = rc + s_cc[slot]
                    + m2.x*q.x + m2.y*q.y + m2.z*q.z + m2.w*q.w;
      if (d < best) { best = d; bj = slot; }
    }
    s_u[tid] = best;
    s_amin[tid] = (short)bj;
  }
  __syncthreads();

  // ---------- phase 4b: column reduction -> prices p = -v ----------
#pragma unroll
  for (int k = 0; k < SPT; ++k) {
    const int slot = tid + k * NT;
    if (slot < K) {
      const float4 q = s_k4[slot];
      const float cc = s_cc[slot];
      float best = BIGF; int br = -1;
      for (int i = 0; i < MTARG; ++i) {
        const float4 m2 = s_m2t[i];
        const float d = s_rc[i] + cc - s_u[i]
                      + m2.x*q.x + m2.y*q.y + m2.z*q.z + m2.w*q.w;
        if (d < best) { best = d; br = i; }
      }
      s_p[slot] = -best;
      s_argr[slot] = (short)br;
    } else if (slot < KMAX) {
      s_p[slot] = 0.0f;
      s_argr[slot] = -1;
    }
  }
  __syncthreads();

  // ---------- phase 4c: greedy tight matching (exact CS start) ----------
  if (tid == 0) {
    for (int i = 0; i < MTARG; ++i) {
      const int j = (int)s_amin[i];
      if (s_row4col[j] < 0) { s_row4col[j] = (short)i; s_col4row[i] = (short)j; }
    }
    for (int j = 0; j < K; ++j) {
      if (s_row4col[j] < 0) {
        const int r = (int)s_argr[j];
        if (r >= 0 && s_col4row[r] < 0) { s_row4col[j] = (short)r; s_col4row[r] = (short)j; }
      }
    }
  }
  __syncthreads();

  // ---------- phase 5: Jacobi epsilon-auction ----------
  for (int sweep = 0; sweep < MAXSWEEP; ++sweep) {
#pragma unroll
    for (int k = 0; k < SPT; ++k) s_bid[tid + k * NT] = 0ull;
    if (tid == 0) s_ucnt = 0;
    __syncthreads();

    if (s_col4row[tid] < 0) {
      const float4 m2 = s_m2t[tid];
      float w1 = BIGF, w2 = BIGF; int j1 = 0;
      for (int j = 0; j < K; ++j) {
        const float4 q = s_k4[j];
        const float v = s_cc[j] + s_p[j]
                      + m2.x*q.x + m2.y*q.y + m2.z*q.z + m2.w*q.w;
        if (v < w1) { w2 = w1; w1 = v; j1 = j; }
        else if (v < w2) { w2 = v; }
      }
      const float b = s_p[j1] + (w2 - w1) + EPSA;
      unsigned int ub = __float_as_uint(b);
      ub = (b >= 0.0f) ? (ub | 0x80000000u) : ~ub;
      atomicMax(&s_bid[j1], ((unsigned long long)ub << 32) | (unsigned int)tid);
    }
    __syncthreads();

#pragma unroll
    for (int k = 0; k < SPT; ++k) {
      const int j = tid + k * NT;
      const unsigned long long bb = s_bid[j];
      if (bb) {
        const int w = (int)(bb & 0xFFFFFFFFull);
        const unsigned int ub = (unsigned int)(bb >> 32);
        const unsigned int rb = (ub & 0x80000000u) ? (ub & 0x7FFFFFFFu) : ~ub;
        const int old = (int)s_row4col[j];
        if (old >= 0) s_col4row[old] = -1;   // evict (old did not bid: race-free)
        s_row4col[j] = (short)w;
        s_col4row[w] = (short)j;
        s_p[j] = __uint_as_float(rb);
      }
    }
    __syncthreads();

    if (s_col4row[tid] < 0) atomicAdd(&s_ucnt, 1);
    __syncthreads();
    if (s_ucnt == 0) break;
  }

  // safety fallback (unreachable in practice): force-assign leftovers
  if (tid == 0 && s_ucnt != 0) {
    for (int i = 0; i < MTARG; ++i) {
      if (s_col4row[i] < 0) {
        for (int j = 0; j < K; ++j) {
          if (s_row4col[j] < 0) { s_row4col[j] = (short)i; s_col4row[i] = (short)j; break; }
        }
      }
    }
  }
  __syncthreads();

  // ---------- phase 6: loss = sum matched full costs - sum lca ----------
  float acc;
  {
    const int j = (int)s_col4row[tid];
    const float4 q = s_k4[j];
    const float4 m2 = s_m2t[tid];
    acc = s_rc[tid] + s_cc[j]
        + m2.x*q.x + m2.y*q.y + m2.z*q.z + m2.w*q.w;
  }
#pragma unroll
  for (int off = 32; off > 0; off >>= 1) acc += __shfl_down(acc, off);
  __syncthreads();
  if ((tid & 63) == 0) s_scr[tid >> 6] = acc;
  __syncthreads();
  if (tid == 0) {
    float s = 0.0f;
    for (int w = 0; w < NW; ++w) s += s_scr[w];
    out[0] = s - s_sumlca;
  }
}

extern "C" void kernel_launch(void* const* d_in, const int* in_sizes, int n_in,
                              void* d_out, int out_size, void* d_ws, size_t ws_size,
                              hipStream_t stream) {
  const float* pred  = (const float*)d_in[0];
  const float* label = (const float*)d_in[1];
  float* out = (float*)d_out;
  hipLaunchKernelGGL(lap_loss_kernel, dim3(1), dim3(NT), 0, stream,
                     pred, label, out);
}

// Round 5
// 803.334 us; speedup vs baseline: 83.8825x; 1.1017x over previous
//
#include <hip/hip_runtime.h>
#include <math.h>

#define ALPHA 0.01f
#define EPSF  1e-5f
#define NPRED 2048
#define MTARG 256
#define NT    256
#define CPT   8            // NPRED / NT
#define KMAX  512
#define SPT   2            // KMAX / NT
#define SPL   8            // KMAX / 64
#define NW    4
#define MARGIN 0.041f      // alpha*4 (max geo term) + fp safety
#define BIGF  1e30f
#define EPSA  0.02f        // auction epsilon
#define MAXSWEEP_A 1024
#define MAXSTEP_B  20000
#define THRESH_B   12
#define QMASK 1023

__launch_bounds__(NT, 1)
__global__ void lap_loss_kernel(const float* __restrict__ pred,
                                const float* __restrict__ label,
                                float* __restrict__ out) {
  __shared__ __align__(16) float s_all[NPRED];
  // kept columns (slot = rank), K <= KMAX
  __shared__ float4 s_k4[KMAX];      // pred coords
  __shared__ float  s_cc[KMAX];      // alpha*|p|^2 + s_j
  __shared__ float  s_cp[KMAX];      // cc + price
  __shared__ short  s_row4col[KMAX];
  __shared__ short  s_argr[KMAX];
  __shared__ unsigned long long s_bid[KMAX];
  // rows (targets)
  __shared__ float  s_u[MTARG];
  __shared__ short  s_col4row[MTARG];
  __shared__ float4 s_m2t[MTARG];
  __shared__ float  s_rc[MTARG];
  __shared__ short  s_amin[MTARG];
  __shared__ short  s_q[QMASK + 1];
  // scratch
  __shared__ float s_redv[NW];
  __shared__ int   s_redj[NW];
  __shared__ float s_scr[NW];
  __shared__ float s_pivot, s_sumlca;
  __shared__ int   s_K, s_ucnt;

  const int tid = threadIdx.x;
  const float* pbase = pred  + (size_t)15 * NPRED * 5;
  const float* lbase = label + (size_t)15 * MTARG * 4;

  // ---------- phase 0: per-column s_j, sum lca over all 2048 ----------
  float mys[CPT];
  float lca_acc = 0.0f;
#pragma unroll
  for (int k = 0; k < CPT; ++k) {
    const int j = tid + k * NT;
    const float c = pbase[j * 5 + 4];
    const float lc  = logf(c + EPSF);
    const float lca = logf(1.0f - c + EPSF);
    mys[k] = lca - lc;
    s_all[j] = mys[k];
    lca_acc += lca;
  }
#pragma unroll
  for (int off = 32; off > 0; off >>= 1) lca_acc += __shfl_down(lca_acc, off);
  if ((tid & 63) == 0) s_scr[tid >> 6] = lca_acc;
  __syncthreads();
  if (tid == 0) {
    float s = 0.0f;
    for (int w = 0; w < NW; ++w) s += s_scr[w];
    s_sumlca = s;
  }

  // ---------- phase 1: exact ranks of s_j (ties by index) ----------
  int myrank[CPT];
#pragma unroll
  for (int k = 0; k < CPT; ++k) myrank[k] = 0;
  {
    const float4* s4 = (const float4*)s_all;
    for (int kk4 = 0; kk4 < NPRED / 4; ++kk4) {
      const float4 sq = s4[kk4];
      const int kb = kk4 * 4;
#pragma unroll
      for (int q = 0; q < 4; ++q) {
        const float sk = (q == 0) ? sq.x : (q == 1) ? sq.y : (q == 2) ? sq.z : sq.w;
        const int kk = kb + q;
#pragma unroll
        for (int k = 0; k < CPT; ++k) {
          const int j = tid + k * NT;
          myrank[k] += (sk < mys[k] || (sk == mys[k] && kk < j)) ? 1 : 0;
        }
      }
    }
  }
#pragma unroll
  for (int k = 0; k < CPT; ++k)
    if (myrank[k] == MTARG - 1) s_pivot = mys[k];
  __syncthreads();

  // ---------- phase 2: compact kept columns (slot = rank) ----------
  {
    const float keepThr = s_pivot + MARGIN;
    int cnt = 0;
#pragma unroll
    for (int k = 0; k < CPT; ++k) {
      const int j = tid + k * NT;
      if (mys[k] <= keepThr && myrank[k] < KMAX) {
        const int slot = myrank[k];
        const float* p = pbase + j * 5;
        const float x = p[0], y = p[1], z = p[2], w = p[3];
        s_k4[slot]   = make_float4(x, y, z, w);
        s_cc[slot]   = ALPHA * (x*x + y*y + z*z + w*w) + mys[k];
        s_row4col[slot] = -1;
        cnt++;
      }
    }
#pragma unroll
    for (int off = 32; off > 0; off >>= 1) cnt += __shfl_down(cnt, off);
    if ((tid & 63) == 0) s_redj[tid >> 6] = cnt;
  }
  {
    const float* t = lbase + tid * 4;
    const float tx = t[0], ty = t[1], tz = t[2], tw = t[3];
    s_m2t[tid] = make_float4(-2.0f*ALPHA*tx, -2.0f*ALPHA*ty, -2.0f*ALPHA*tz, -2.0f*ALPHA*tw);
    s_rc[tid]  = ALPHA * (tx*tx + ty*ty + tz*tz + tw*tw);
    s_col4row[tid] = -1;
  }
  __syncthreads();
  if (tid == 0) {
    int K = 0;
    for (int w = 0; w < NW; ++w) K += s_redj[w];
    s_K = K;
  }
  __syncthreads();
  const int K = s_K;

  // ---------- phase 4: row reduction (u = row minima of full cost) ----------
  {
    const float4 m2 = s_m2t[tid];
    const float  rc = s_rc[tid];
    float best = BIGF; int bj = 0;
    for (int slot = 0; slot < K; ++slot) {
      const float4 q = s_k4[slot];
      const float d = rc + s_cc[slot]
                    + m2.x*q.x + m2.y*q.y + m2.z*q.z + m2.w*q.w;
      if (d < best) { best = d; bj = slot; }
    }
    s_u[tid] = best;
    s_amin[tid] = (short)bj;
  }
  __syncthreads();

  // ---------- phase 4b: column reduction -> cp = cc + p, p = -colmin ----------
#pragma unroll
  for (int k = 0; k < SPT; ++k) {
    const int slot = tid + k * NT;
    if (slot < K) {
      const float4 q = s_k4[slot];
      const float cc = s_cc[slot];
      float best = BIGF; int br = -1;
      for (int i = 0; i < MTARG; ++i) {
        const float4 m2 = s_m2t[i];
        const float d = s_rc[i] + cc - s_u[i]
                      + m2.x*q.x + m2.y*q.y + m2.z*q.z + m2.w*q.w;
        if (d < best) { best = d; br = i; }
      }
      s_cp[slot] = cc - best;       // cc + p, p = -best
      s_argr[slot] = (short)br;
    } else if (slot < KMAX) {
      s_cp[slot] = BIGF;
      s_argr[slot] = -1;
    }
  }
  __syncthreads();

  // ---------- phase 4c: greedy tight matching ----------
  if (tid == 0) {
    for (int i = 0; i < MTARG; ++i) {
      const int j = (int)s_amin[i];
      if (s_row4col[j] < 0) { s_row4col[j] = (short)i; s_col4row[i] = (short)j; }
    }
    for (int j = 0; j < K; ++j) {
      if (s_row4col[j] < 0) {
        const int r = (int)s_argr[j];
        if (r >= 0 && s_col4row[r] < 0) { s_row4col[j] = (short)r; s_col4row[r] = (short)j; }
      }
    }
  }
  __syncthreads();

  // ---------- phase 5A: Jacobi epsilon-auction (bulk) ----------
  for (int sweep = 0; sweep < MAXSWEEP_A; ++sweep) {
#pragma unroll
    for (int k = 0; k < SPT; ++k) s_bid[tid + k * NT] = 0ull;
    if (tid == 0) s_ucnt = 0;
    __syncthreads();

    if (s_col4row[tid] < 0) {
      atomicAdd(&s_ucnt, 1);
      const float4 m2 = s_m2t[tid];
      float w1 = BIGF, w2 = BIGF; int j1 = 0;
      for (int j = 0; j < K; ++j) {
        const float4 q = s_k4[j];
        const float v = s_cp[j]
                      + m2.x*q.x + m2.y*q.y + m2.z*q.z + m2.w*q.w;
        if (v < w1) { w2 = w1; w1 = v; j1 = j; }
        else if (v < w2) { w2 = v; }
      }
      const float ncp = s_cp[j1] + (w2 - w1) + EPSA;   // new cc+p (monotone in bid)
      unsigned int ub = __float_as_uint(ncp);
      ub = (ncp >= 0.0f) ? (ub | 0x80000000u) : ~ub;
      atomicMax(&s_bid[j1], ((unsigned long long)ub << 32) | (unsigned int)tid);
    }
    __syncthreads();

#pragma unroll
    for (int k = 0; k < SPT; ++k) {
      const int j = tid + k * NT;
      const unsigned long long bb = s_bid[j];
      if (bb) {
        const int w = (int)(bb & 0xFFFFFFFFull);
        const unsigned int ub = (unsigned int)(bb >> 32);
        const unsigned int rb = (ub & 0x80000000u) ? (ub & 0x7FFFFFFFu) : ~ub;
        const int old = (int)s_row4col[j];
        if (old >= 0) s_col4row[old] = -1;
        s_row4col[j] = (short)w;
        s_col4row[w] = (short)j;
        s_cp[j] = __uint_as_float(rb);
      }
    }
    const int ucnt = s_ucnt;   // stable since pre-resolve barrier
    __syncthreads();
    if (ucnt <= THRESH_B) break;
  }

  // ---------- phase 5B: single-wave Gauss-Seidel auction (tail) ----------
  if (tid < 64) {
    const int lane = tid;
    // deterministic ballot-compacted queue of unassigned rows
    int tail = 0;
#pragma unroll
    for (int q = 0; q < 4; ++q) {
      const int row = lane + 64 * q;
      const bool un = (s_col4row[row] < 0);
      const unsigned long long m = __ballot(un);
      const int pos = tail + __popcll(m & ((1ull << lane) - 1ull));
      if (un) s_q[pos] = (short)row;
      tail += (int)__popcll(m);
    }
    int head = 0;
    for (int step = 0; step < MAXSTEP_B && head < tail; ++step) {
      const int r = (int)s_q[head & QMASK]; ++head;
      const float4 m2 = s_m2t[r];
      float w1 = BIGF, w2 = BIGF; int j1 = 0x7FFFFFFF;
#pragma unroll
      for (int k = 0; k < SPL; ++k) {
        const int slot = lane + 64 * k;
        if (slot < K) {
          const float4 q4 = s_k4[slot];
          const float v = s_cp[slot]
                        + m2.x*q4.x + m2.y*q4.y + m2.z*q4.z + m2.w*q4.w;
          if (v < w1) { w2 = w1; w1 = v; j1 = slot; }
          else if (v < w2) { w2 = v; }
        }
      }
      // 64-lane top-2 butterfly merge (deterministic, index tie-break)
#pragma unroll
      for (int off = 1; off < 64; off <<= 1) {
        const float ow1 = __shfl_xor(w1, off);
        const float ow2 = __shfl_xor(w2, off);
        const int   oj1 = __shfl_xor(j1, off);
        if (ow1 < w1 || (ow1 == w1 && oj1 < j1)) {
          w2 = fminf(w1, ow2); w1 = ow1; j1 = oj1;
        } else {
          w2 = fminf(w2, ow1);
        }
      }
      const float inc = (w2 - w1) + EPSA;
      const int old = (int)s_row4col[j1];   // broadcast read BEFORE write
      if (lane == 0) {
        s_cp[j1] += inc;
        s_row4col[j1] = (short)r;
        s_col4row[r] = (short)j1;
        if (old >= 0) { s_col4row[old] = -1; s_q[tail & QMASK] = (short)old; }
      }
      if (old >= 0) ++tail;
      __threadfence_block();
    }
    // safety fallback (unreachable in practice)
    if (lane == 0 && head < tail) {
      for (int i = 0; i < MTARG; ++i) {
        if (s_col4row[i] < 0) {
          for (int j = 0; j < K; ++j) {
            if (s_row4col[j] < 0) { s_row4col[j] = (short)i; s_col4row[i] = (short)j; break; }
          }
        }
      }
    }
  }
  __syncthreads();

  // ---------- phase 6: loss = sum matched full costs - sum lca ----------
  float acc;
  {
    const int j = (int)s_col4row[tid];
    const float4 q = s_k4[j];
    const float4 m2 = s_m2t[tid];
    acc = s_rc[tid] + s_cc[j]
        + m2.x*q.x + m2.y*q.y + m2.z*q.z + m2.w*q.w;
  }
#pragma unroll
  for (int off = 32; off > 0; off >>= 1) acc += __shfl_down(acc, off);
  __syncthreads();
  if ((tid & 63) == 0) s_scr[tid >> 6] = acc;
  __syncthreads();
  if (tid == 0) {
    float s = 0.0f;
    for (int w = 0; w < NW; ++w) s += s_scr[w];
    out[0] = s - s_sumlca;
  }
}

extern "C" void kernel_launch(void* const* d_in, const int* in_sizes, int n_in,
                              void* d_out, int out_size, void* d_ws, size_t ws_size,
                              hipStream_t stream) {
  const float* pred  = (const float*)d_in[0];
  const float* label = (const float*)d_in[1];
  float* out = (float*)d_out;
  hipLaunchKernelGGL(lap_loss_kernel, dim3(1), dim3(NT), 0, stream,
                     pred, label, out);
}

// Round 6
// 763.801 us; speedup vs baseline: 88.2241x; 1.0518x over previous
//
#include <hip/hip_runtime.h>
#include <math.h>

#define ALPHA 0.01f
#define EPSF  1e-5f
#define NPRED 2048
#define MTARG 256
#define NT    256
#define CPT   8            // NPRED / NT
#define KMAX  512
#define SPT   2            // KMAX / NT
#define SPL   8            // KMAX / 64
#define NW    4
#define MARGIN 0.041f      // alpha*4 (max geo term) + fp safety
#define BIGF  1e30f
#define EPSA  0.02f        // auction epsilon
#define MAXSWEEP_A 1024
#define MAXSTEP_B  20000
#define THRESH_B   12
#define QMASK 1023

__launch_bounds__(NT, 1)
__global__ void lap_loss_kernel(const float* __restrict__ pred,
                                const float* __restrict__ label,
                                float* __restrict__ out) {
  __shared__ __align__(16) float s_all[NPRED];
  // kept columns (slot = rank), K <= KMAX
  __shared__ float4 s_k4[KMAX];      // pred coords
  __shared__ float  s_cc[KMAX];      // alpha*|p|^2 + s_j
  __shared__ float  s_cp[KMAX];      // cc + price
  __shared__ short  s_row4col[KMAX];
  __shared__ short  s_argr[KMAX];
  __shared__ unsigned long long s_bid[KMAX];
  // rows (targets)
  __shared__ float  s_u[MTARG];
  __shared__ short  s_col4row[MTARG];
  __shared__ float4 s_m2t[MTARG];
  __shared__ float  s_rc[MTARG];
  __shared__ short  s_amin[MTARG];
  __shared__ short  s_q[QMASK + 1];
  // scratch
  __shared__ float s_redv[NW];
  __shared__ int   s_redj[NW];
  __shared__ float s_scr[NW];
  __shared__ float s_pivot, s_sumlca;
  __shared__ int   s_K, s_qn;

  const int tid = threadIdx.x;
  const float* pbase = pred  + (size_t)15 * NPRED * 5;
  const float* lbase = label + (size_t)15 * MTARG * 4;

  // ---------- phase 0: per-column s_j, sum lca over all 2048 ----------
  float mys[CPT];
  float lca_acc = 0.0f;
#pragma unroll
  for (int k = 0; k < CPT; ++k) {
    const int j = tid + k * NT;
    const float c = pbase[j * 5 + 4];
    const float lc  = logf(c + EPSF);
    const float lca = logf(1.0f - c + EPSF);
    mys[k] = lca - lc;
    s_all[j] = mys[k];
    lca_acc += lca;
  }
#pragma unroll
  for (int off = 32; off > 0; off >>= 1) lca_acc += __shfl_down(lca_acc, off);
  if ((tid & 63) == 0) s_scr[tid >> 6] = lca_acc;
  __syncthreads();
  if (tid == 0) {
    float s = 0.0f;
    for (int w = 0; w < NW; ++w) s += s_scr[w];
    s_sumlca = s;
    s_qn = 0;
  }

  // ---------- phase 1: exact ranks of s_j (ties by index) ----------
  int myrank[CPT];
#pragma unroll
  for (int k = 0; k < CPT; ++k) myrank[k] = 0;
  {
    const float4* s4 = (const float4*)s_all;
    for (int kk4 = 0; kk4 < NPRED / 4; ++kk4) {
      const float4 sq = s4[kk4];
      const int kb = kk4 * 4;
#pragma unroll
      for (int q = 0; q < 4; ++q) {
        const float sk = (q == 0) ? sq.x : (q == 1) ? sq.y : (q == 2) ? sq.z : sq.w;
        const int kk = kb + q;
#pragma unroll
        for (int k = 0; k < CPT; ++k) {
          const int j = tid + k * NT;
          myrank[k] += (sk < mys[k] || (sk == mys[k] && kk < j)) ? 1 : 0;
        }
      }
    }
  }
#pragma unroll
  for (int k = 0; k < CPT; ++k)
    if (myrank[k] == MTARG - 1) s_pivot = mys[k];
  __syncthreads();

  // ---------- phase 2: compact kept columns (slot = rank), clear bid board ----------
  {
    const float keepThr = s_pivot + MARGIN;
    int cnt = 0;
#pragma unroll
    for (int k = 0; k < CPT; ++k) {
      const int j = tid + k * NT;
      if (mys[k] <= keepThr && myrank[k] < KMAX) {
        const int slot = myrank[k];
        const float* p = pbase + j * 5;
        const float x = p[0], y = p[1], z = p[2], w = p[3];
        s_k4[slot]   = make_float4(x, y, z, w);
        s_cc[slot]   = ALPHA * (x*x + y*y + z*z + w*w) + mys[k];
        s_row4col[slot] = -1;
        cnt++;
      }
    }
#pragma unroll
    for (int off = 32; off > 0; off >>= 1) cnt += __shfl_down(cnt, off);
    if ((tid & 63) == 0) s_redj[tid >> 6] = cnt;
  }
#pragma unroll
  for (int k = 0; k < SPT; ++k) s_bid[tid + k * NT] = 0ull;
  {
    const float* t = lbase + tid * 4;
    const float tx = t[0], ty = t[1], tz = t[2], tw = t[3];
    s_m2t[tid] = make_float4(-2.0f*ALPHA*tx, -2.0f*ALPHA*ty, -2.0f*ALPHA*tz, -2.0f*ALPHA*tw);
    s_rc[tid]  = ALPHA * (tx*tx + ty*ty + tz*tz + tw*tw);
    s_col4row[tid] = -1;
  }
  __syncthreads();
  if (tid == 0) {
    int K = 0;
    for (int w = 0; w < NW; ++w) K += s_redj[w];
    s_K = K;
  }
  __syncthreads();
  const int K = s_K;

  // ---------- phase 4: row reduction (u = row minima of full cost) ----------
  {
    const float4 m2 = s_m2t[tid];
    const float  rc = s_rc[tid];
    float best = BIGF; int bj = 0;
    for (int slot = 0; slot < K; ++slot) {
      const float4 q = s_k4[slot];
      const float d = rc + s_cc[slot]
                    + m2.x*q.x + m2.y*q.y + m2.z*q.z + m2.w*q.w;
      if (d < best) { best = d; bj = slot; }
    }
    s_u[tid] = best;
    s_amin[tid] = (short)bj;
  }
  __syncthreads();

  // ---------- phase 4b: column reduction -> cp = cc + p, p = -colmin ----------
#pragma unroll
  for (int k = 0; k < SPT; ++k) {
    const int slot = tid + k * NT;
    if (slot < K) {
      const float4 q = s_k4[slot];
      const float cc = s_cc[slot];
      float best = BIGF; int br = -1;
      for (int i = 0; i < MTARG; ++i) {
        const float4 m2 = s_m2t[i];
        const float d = s_rc[i] + cc - s_u[i]
                      + m2.x*q.x + m2.y*q.y + m2.z*q.z + m2.w*q.w;
        if (d < best) { best = d; br = i; }
      }
      s_cp[slot] = cc - best;       // cc + p, p = -best
      s_argr[slot] = (short)br;
    } else if (slot < KMAX) {
      s_cp[slot] = BIGF;
      s_argr[slot] = -1;
    }
  }
  __syncthreads();

  // ---------- phase 4c: greedy tight matching ----------
  if (tid == 0) {
    for (int i = 0; i < MTARG; ++i) {
      const int j = (int)s_amin[i];
      if (s_row4col[j] < 0) { s_row4col[j] = (short)i; s_col4row[i] = (short)j; }
    }
    for (int j = 0; j < K; ++j) {
      if (s_row4col[j] < 0) {
        const int r = (int)s_argr[j];
        if (r >= 0 && s_col4row[r] < 0) { s_row4col[j] = (short)r; s_col4row[r] = (short)j; }
      }
    }
  }
  __syncthreads();

  // ---------- phase 5A: Jacobi epsilon-auction, bidder-compacted ----------
  for (int sweep = 0; sweep < MAXSWEEP_A; ++sweep) {
    // compact unassigned rows into s_q[0..U)  (order across waves may vary;
    // result is order-independent: bids resolved by max with row tie-break)
    const bool un = (s_col4row[tid] < 0);
    const unsigned long long m = __ballot(un);
    const int lane = tid & 63;
    int base = 0;
    if (lane == 0) base = atomicAdd(&s_qn, (int)__popcll(m));
    base = __shfl(base, 0);
    if (un) s_q[base + (int)__popcll(m & ((1ull << lane) - 1ull))] = (short)tid;
    __syncthreads();
    const int U = s_qn;
    if (U <= THRESH_B) break;          // includes U == 0

    // bid: threads 0..U-1, rows from queue (1 wave active once U <= 64)
    if (tid < U) {
      const int r = (int)s_q[tid];
      const float4 m2 = s_m2t[r];
      float w1 = BIGF, w2 = BIGF; int j1 = 0;
      for (int j = 0; j < K; ++j) {
        const float4 q = s_k4[j];
        const float v = s_cp[j]
                      + m2.x*q.x + m2.y*q.y + m2.z*q.z + m2.w*q.w;
        if (v < w1) { w2 = w1; w1 = v; j1 = j; }
        else if (v < w2) { w2 = v; }
      }
      const float ncp = s_cp[j1] + (w2 - w1) + EPSA;   // new cc+p (monotone in bid)
      unsigned int ub = __float_as_uint(ncp);
      ub = (ncp >= 0.0f) ? (ub | 0x80000000u) : ~ub;
      atomicMax(&s_bid[j1], ((unsigned long long)ub << 32) | (unsigned int)r);
    }
    __syncthreads();

    // resolve winners, clear bid slots, reset queue counter
#pragma unroll
    for (int k = 0; k < SPT; ++k) {
      const int j = tid + k * NT;
      const unsigned long long bb = s_bid[j];
      if (bb) {
        s_bid[j] = 0ull;
        const int w = (int)(bb & 0xFFFFFFFFull);
        const unsigned int ub = (unsigned int)(bb >> 32);
        const unsigned int rb = (ub & 0x80000000u) ? (ub & 0x7FFFFFFFu) : ~ub;
        const int old = (int)s_row4col[j];
        if (old >= 0) s_col4row[old] = -1;
        s_row4col[j] = (short)w;
        s_col4row[w] = (short)j;
        s_cp[j] = __uint_as_float(rb);
      }
    }
    if (tid == 0) s_qn = 0;
    __syncthreads();
  }

  // ---------- phase 5B: single-wave Gauss-Seidel auction (tail) ----------
  if (tid < 64) {
    const int lane = tid;
    // deterministic ballot-compacted queue of unassigned rows
    int tail = 0;
#pragma unroll
    for (int q = 0; q < 4; ++q) {
      const int row = lane + 64 * q;
      const bool un = (s_col4row[row] < 0);
      const unsigned long long m = __ballot(un);
      const int pos = tail + (int)__popcll(m & ((1ull << lane) - 1ull));
      if (un) s_q[pos] = (short)row;
      tail += (int)__popcll(m);
    }
    int head = 0;
    for (int step = 0; step < MAXSTEP_B && head < tail; ++step) {
      const int r = (int)s_q[head & QMASK]; ++head;
      const float4 m2 = s_m2t[r];
      float w1 = BIGF, w2 = BIGF; int j1 = 0x7FFFFFFF;
#pragma unroll
      for (int k = 0; k < SPL; ++k) {
        const int slot = lane + 64 * k;
        if (slot < K) {
          const float4 q4 = s_k4[slot];
          const float v = s_cp[slot]
                        + m2.x*q4.x + m2.y*q4.y + m2.z*q4.z + m2.w*q4.w;
          if (v < w1) { w2 = w1; w1 = v; j1 = slot; }
          else if (v < w2) { w2 = v; }
        }
      }
      // 64-lane top-2 butterfly merge (deterministic, index tie-break)
#pragma unroll
      for (int off = 1; off < 64; off <<= 1) {
        const float ow1 = __shfl_xor(w1, off);
        const float ow2 = __shfl_xor(w2, off);
        const int   oj1 = __shfl_xor(j1, off);
        if (ow1 < w1 || (ow1 == w1 && oj1 < j1)) {
          w2 = fminf(w1, ow2); w1 = ow1; j1 = oj1;
        } else {
          w2 = fminf(w2, ow1);
        }
      }
      const float inc = (w2 - w1) + EPSA;
      const int old = (int)s_row4col[j1];   // broadcast read BEFORE write
      if (lane == 0) {
        s_cp[j1] += inc;
        s_row4col[j1] = (short)r;
        s_col4row[r] = (short)j1;
        if (old >= 0) { s_col4row[old] = -1; s_q[tail & QMASK] = (short)old; }
      }
      if (old >= 0) ++tail;
      __threadfence_block();
    }
    // safety fallback (unreachable in practice)
    if (lane == 0 && head < tail) {
      for (int i = 0; i < MTARG; ++i) {
        if (s_col4row[i] < 0) {
          for (int j = 0; j < K; ++j) {
            if (s_row4col[j] < 0) { s_row4col[j] = (short)i; s_col4row[i] = (short)j; break; }
          }
        }
      }
    }
  }
  __syncthreads();

  // ---------- phase 6: loss = sum matched full costs - sum lca ----------
  float acc;
  {
    const int j = (int)s_col4row[tid];
    const float4 q = s_k4[j];
    const float4 m2 = s_m2t[tid];
    acc = s_rc[tid] + s_cc[j]
        + m2.x*q.x + m2.y*q.y + m2.z*q.z + m2.w*q.w;
  }
#pragma unroll
  for (int off = 32; off > 0; off >>= 1) acc += __shfl_down(acc, off);
  __syncthreads();
  if ((tid & 63) == 0) s_scr[tid >> 6] = acc;
  __syncthreads();
  if (tid == 0) {
    float s = 0.0f;
    for (int w = 0; w < NW; ++w) s += s_scr[w];
    out[0] = s - s_sumlca;
  }
}

extern "C" void kernel_launch(void* const* d_in, const int* in_sizes, int n_in,
                              void* d_out, int out_size, void* d_ws, size_t ws_size,
                              hipStream_t stream) {
  const float* pred  = (const float*)d_in[0];
  const float* label = (const float*)d_in[1];
  float* out = (float*)d_out;
  hipLaunchKernelGGL(lap_loss_kernel, dim3(1), dim3(NT), 0, stream,
                     pred, label, out);
}

// Round 7
// 629.668 us; speedup vs baseline: 107.0177x; 1.2130x over previous
//
#include <hip/hip_runtime.h>
#include <math.h>

#define ALPHA 0.01f
#define EPSF  1e-5f
#define NPRED 2048
#define MTARG 256
#define NT    256
#define CPT   8            // NPRED / NT
#define KMAX  512
#define SPT   2            // KMAX / NT
#define SPL   8            // KMAX / 64
#define NW    4
#define MARGIN 0.041f      // alpha*4 (max geo term) + fp safety
#define BIGF  1e30f
#define EPSA  0.02f        // auction epsilon
#define MAXSWEEP_A 1024
#define MAXSTEP_B  20000
#define THRESH_B   8
#define QMASK 1023
#define IINF 0x7FFFFFFF

__device__ __forceinline__ unsigned int ordf(float v) {
  const unsigned int b = __float_as_uint(v);
  return (v >= 0.0f) ? (b | 0x80000000u) : ~b;
}
__device__ __forceinline__ float unordf(unsigned int u) {
  return __uint_as_float((u & 0x80000000u) ? (u & 0x7FFFFFFFu) : ~u);
}

__launch_bounds__(NT, 1)
__global__ void lap_loss_kernel(const float* __restrict__ pred,
                                const float* __restrict__ label,
                                float* __restrict__ out) {
  __shared__ __align__(16) float s_all[NPRED];
  // kept columns (slot = rank), K <= KMAX
  __shared__ float4 s_k4[KMAX];      // pred coords
  __shared__ float  s_cc[KMAX];      // alpha*|p|^2 + s_j
  __shared__ float  s_cp[KMAX];      // cc + price
  __shared__ short  s_row4col[KMAX];
  __shared__ short  s_argr[KMAX];
  __shared__ unsigned long long s_bid[KMAX];
  __shared__ int    s_bC[KMAX];      // greedy pass-A board
  // rows (targets)
  __shared__ float  s_u[MTARG];
  __shared__ short  s_col4row[MTARG];
  __shared__ float4 s_m2t[MTARG];
  __shared__ float  s_rc[MTARG];
  __shared__ short  s_amin[MTARG];
  __shared__ int    s_bR[MTARG];     // greedy pass-B board
  __shared__ short  s_q[QMASK + 1];
  // scratch
  __shared__ float s_redv[NW];
  __shared__ int   s_redj[NW];
  __shared__ float s_scr[NW];
  __shared__ float s_pivot, s_sumlca;
  __shared__ int   s_K, s_qn;

  const int tid = threadIdx.x;
  const float* pbase = pred  + (size_t)15 * NPRED * 5;
  const float* lbase = label + (size_t)15 * MTARG * 4;

  // ---------- phase 0: per-column s_j, sum lca over all 2048 ----------
  float mys[CPT];
  float lca_acc = 0.0f;
#pragma unroll
  for (int k = 0; k < CPT; ++k) {
    const int j = tid + k * NT;
    const float c = pbase[j * 5 + 4];
    const float lc  = logf(c + EPSF);
    const float lca = logf(1.0f - c + EPSF);
    mys[k] = lca - lc;
    s_all[j] = mys[k];
    lca_acc += lca;
  }
#pragma unroll
  for (int off = 32; off > 0; off >>= 1) lca_acc += __shfl_down(lca_acc, off);
  if ((tid & 63) == 0) s_scr[tid >> 6] = lca_acc;
  __syncthreads();
  if (tid == 0) {
    float s = 0.0f;
    for (int w = 0; w < NW; ++w) s += s_scr[w];
    s_sumlca = s;
    s_qn = 0;
  }

  // ---------- phase 1: exact ranks of s_j (ties by index) ----------
  int myrank[CPT];
#pragma unroll
  for (int k = 0; k < CPT; ++k) myrank[k] = 0;
  {
    const float4* s4 = (const float4*)s_all;
    for (int kk4 = 0; kk4 < NPRED / 4; ++kk4) {
      const float4 sq = s4[kk4];
      const int kb = kk4 * 4;
#pragma unroll
      for (int q = 0; q < 4; ++q) {
        const float sk = (q == 0) ? sq.x : (q == 1) ? sq.y : (q == 2) ? sq.z : sq.w;
        const int kk = kb + q;
#pragma unroll
        for (int k = 0; k < CPT; ++k) {
          const int j = tid + k * NT;
          myrank[k] += (sk < mys[k] || (sk == mys[k] && kk < j)) ? 1 : 0;
        }
      }
    }
  }
#pragma unroll
  for (int k = 0; k < CPT; ++k)
    if (myrank[k] == MTARG - 1) s_pivot = mys[k];
  __syncthreads();

  // ---------- phase 2: compact kept columns; init boards ----------
  {
    const float keepThr = s_pivot + MARGIN;
    int cnt = 0;
#pragma unroll
    for (int k = 0; k < CPT; ++k) {
      const int j = tid + k * NT;
      if (mys[k] <= keepThr && myrank[k] < KMAX) {
        const int slot = myrank[k];
        const float* p = pbase + j * 5;
        const float x = p[0], y = p[1], z = p[2], w = p[3];
        s_k4[slot]   = make_float4(x, y, z, w);
        s_cc[slot]   = ALPHA * (x*x + y*y + z*z + w*w) + mys[k];
        s_row4col[slot] = -1;
        cnt++;
      }
    }
#pragma unroll
    for (int off = 32; off > 0; off >>= 1) cnt += __shfl_down(cnt, off);
    if ((tid & 63) == 0) s_redj[tid >> 6] = cnt;
  }
#pragma unroll
  for (int k = 0; k < SPT; ++k) {
    s_bid[tid + k * NT] = 0ull;
    s_bC[tid + k * NT]  = IINF;
  }
  {
    const float* t = lbase + tid * 4;
    const float tx = t[0], ty = t[1], tz = t[2], tw = t[3];
    s_m2t[tid] = make_float4(-2.0f*ALPHA*tx, -2.0f*ALPHA*ty, -2.0f*ALPHA*tz, -2.0f*ALPHA*tw);
    s_rc[tid]  = ALPHA * (tx*tx + ty*ty + tz*tz + tw*tw);
    s_col4row[tid] = -1;
    s_bR[tid] = IINF;
  }
  __syncthreads();
  if (tid == 0) {
    int K = 0;
    for (int w = 0; w < NW; ++w) K += s_redj[w];
    s_K = K;
  }
  __syncthreads();
  const int K = s_K;

  // ---------- phase 4: row reduction (u = row minima of full cost) ----------
  {
    const float4 m2 = s_m2t[tid];
    const float  rc = s_rc[tid];
    float best = BIGF; int bj = 0;
    for (int slot = 0; slot < K; ++slot) {
      const float4 q = s_k4[slot];
      const float d = rc + s_cc[slot]
                    + m2.x*q.x + m2.y*q.y + m2.z*q.z + m2.w*q.w;
      if (d < best) { best = d; bj = slot; }
    }
    s_u[tid] = best;
    s_amin[tid] = (short)bj;
  }
  __syncthreads();

  // ---------- phase 4b: column reduction -> cp = cc + p, p = -colmin ----------
#pragma unroll
  for (int k = 0; k < SPT; ++k) {
    const int slot = tid + k * NT;
    if (slot < K) {
      const float4 q = s_k4[slot];
      const float cc = s_cc[slot];
      float best = BIGF; int br = -1;
      for (int i = 0; i < MTARG; ++i) {
        const float4 m2 = s_m2t[i];
        const float d = s_rc[i] + cc - s_u[i]
                      + m2.x*q.x + m2.y*q.y + m2.z*q.z + m2.w*q.w;
        if (d < best) { best = d; br = i; }
      }
      s_cp[slot] = cc - best;       // cc + p, p = -best
      s_argr[slot] = (short)br;
    } else if (slot < KMAX) {
      s_cp[slot] = BIGF;
      s_argr[slot] = -1;
    }
  }
  __syncthreads();

  // ---------- phase 4c: greedy tight matching (parallel, == serial result) ----------
  // pass A: each row proposes to its argmin column; column takes min row
  atomicMin(&s_bC[(int)s_amin[tid]], tid);
  __syncthreads();
#pragma unroll
  for (int k = 0; k < SPT; ++k) {
    const int j = tid + k * NT;
    if (j < K) {
      const int w = s_bC[j];
      if (w != IINF) { s_row4col[j] = (short)w; s_col4row[w] = (short)j; }
    }
  }
  __syncthreads();
  // pass B: unmatched column proposes to its argmin row (if free); row takes min column
#pragma unroll
  for (int k = 0; k < SPT; ++k) {
    const int j = tid + k * NT;
    if (j < K && s_row4col[j] < 0) {
      const int r = (int)s_argr[j];
      if (r >= 0 && s_col4row[r] < 0) atomicMin(&s_bR[r], j);
    }
  }
  __syncthreads();
  {
    const int j = s_bR[tid];
    if (s_col4row[tid] < 0 && j != IINF) {
      s_col4row[tid] = (short)j;
      s_row4col[j] = (short)tid;
    }
  }
  __syncthreads();

  // ---------- phase 5A: Jacobi epsilon-auction, grouped bidders ----------
  for (int sweep = 0; sweep < MAXSWEEP_A; ++sweep) {
    // compact unassigned rows into s_q[0..U)
    const bool un = (s_col4row[tid] < 0);
    const unsigned long long m = __ballot(un);
    const int lane = tid & 63;
    int base = 0;
    if (lane == 0) base = atomicAdd(&s_qn, (int)__popcll(m));
    base = __shfl(base, 0);
    if (un) s_q[base + (int)__popcll(m & ((1ull << lane) - 1ull))] = (short)tid;
    __syncthreads();
    const int U = s_qn;
    if (U <= THRESH_B) break;          // includes U == 0

    // grouped bid: G threads per bidder, G = 2^floor(log2(256/U)) capped 64
    {
      int G = 256 / U;
      G = 1 << (31 - __builtin_clz(G));
      if (G > 64) G = 64;
      const int lg = 31 - __builtin_clz(G);
      if (tid < (U << lg)) {
        const int b = tid >> lg;
        const int l = tid & (G - 1);
        const int r = (int)s_q[b];
        const float4 m2 = s_m2t[r];
        unsigned long long key = ~0ull;
        unsigned int w2u = 0xFFFFFFFFu;
        for (int j = l; j < K; j += G) {
          const float4 q = s_k4[j];
          const float v = s_cp[j]
                        + m2.x*q.x + m2.y*q.y + m2.z*q.z + m2.w*q.w;
          const unsigned long long k2 =
              ((unsigned long long)ordf(v) << 32) | (unsigned int)j;
          if (k2 < key) { w2u = (unsigned int)(key >> 32); key = k2; }
          else { const unsigned int o = (unsigned int)(k2 >> 32); if (o < w2u) w2u = o; }
        }
        for (int off = 1; off < G; off <<= 1) {
          const unsigned long long ok = __shfl_xor(key, off);
          const unsigned int ow2 = __shfl_xor(w2u, off);
          if (ok < key) {
            const unsigned int v1 = (unsigned int)(key >> 32);
            w2u = (ow2 < v1) ? ow2 : v1;
            key = ok;
          } else {
            const unsigned int o1 = (unsigned int)(ok >> 32);
            if (o1 < w2u) w2u = o1;
          }
        }
        if (l == 0) {
          const int j1 = (int)(key & 0xFFFFFFFFull);
          const float w1f = unordf((unsigned int)(key >> 32));
          const float w2f = unordf(w2u);
          const float ncp = s_cp[j1] + (w2f - w1f) + EPSA;
          atomicMax(&s_bid[j1],
                    ((unsigned long long)ordf(ncp) << 32) | (unsigned int)r);
        }
      }
    }
    __syncthreads();

    // resolve winners, clear bid slots, reset queue counter
#pragma unroll
    for (int k = 0; k < SPT; ++k) {
      const int j = tid + k * NT;
      const unsigned long long bb = s_bid[j];
      if (bb) {
        s_bid[j] = 0ull;
        const int w = (int)(bb & 0xFFFFFFFFull);
        const unsigned int ub = (unsigned int)(bb >> 32);
        const int old = (int)s_row4col[j];
        if (old >= 0) s_col4row[old] = -1;
        s_row4col[j] = (short)w;
        s_col4row[w] = (short)j;
        s_cp[j] = unordf(ub);
      }
    }
    if (tid == 0) s_qn = 0;
    __syncthreads();
  }

  // ---------- phase 5B: single-wave register-resident Gauss-Seidel ----------
  if (tid < 64) {
    const int lane = tid;
    // column state in registers: coords + current cp
    float kx[SPL], ky[SPL], kz[SPL], kw[SPL], cpr[SPL];
#pragma unroll
    for (int k = 0; k < SPL; ++k) {
      const int slot = lane + 64 * k;
      if (slot < K) {
        const float4 q = s_k4[slot];
        kx[k] = q.x; ky[k] = q.y; kz[k] = q.z; kw[k] = q.w;
        cpr[k] = s_cp[slot];
      } else {
        kx[k] = 0.f; ky[k] = 0.f; kz[k] = 0.f; kw[k] = 0.f;
        cpr[k] = BIGF;
      }
    }
    // deterministic ballot-compacted queue of unassigned rows
    int tail = 0;
#pragma unroll
    for (int q = 0; q < 4; ++q) {
      const int row = lane + 64 * q;
      const bool un = (s_col4row[row] < 0);
      const unsigned long long m = __ballot(un);
      const int pos = tail + (int)__popcll(m & ((1ull << lane) - 1ull));
      if (un) s_q[pos] = (short)row;
      tail += (int)__popcll(m);
    }
    int head = 0;
    for (int step = 0; step < MAXSTEP_B && head < tail; ++step) {
      const int r = (int)s_q[head & QMASK]; ++head;
      const float4 m2 = s_m2t[r];
      unsigned long long key = ~0ull;
      unsigned int w2u = 0xFFFFFFFFu;
#pragma unroll
      for (int k = 0; k < SPL; ++k) {
        const float v = cpr[k]
                      + m2.x*kx[k] + m2.y*ky[k] + m2.z*kz[k] + m2.w*kw[k];
        const unsigned long long k2 =
            ((unsigned long long)ordf(v) << 32) | (unsigned int)(lane + 64 * k);
        if (k2 < key) { w2u = (unsigned int)(key >> 32); key = k2; }
        else { const unsigned int o = (unsigned int)(k2 >> 32); if (o < w2u) w2u = o; }
      }
#pragma unroll
      for (int off = 1; off < 64; off <<= 1) {
        const unsigned long long ok = __shfl_xor(key, off);
        const unsigned int ow2 = __shfl_xor(w2u, off);
        if (ok < key) {
          const unsigned int v1 = (unsigned int)(key >> 32);
          w2u = (ow2 < v1) ? ow2 : v1;
          key = ok;
        } else {
          const unsigned int o1 = (unsigned int)(ok >> 32);
          if (o1 < w2u) w2u = o1;
        }
      }
      const int j1 = (int)(key & 0xFFFFFFFFull);
      const float inc = (unordf(w2u) - unordf((unsigned int)(key >> 32))) + EPSA;
      const int bl = j1 & 63, bk = j1 >> 6;
      if (lane == bl) {
#pragma unroll
        for (int k = 0; k < SPL; ++k) if (k == bk) cpr[k] += inc;
      }
      const int old = (int)s_row4col[j1];   // broadcast read BEFORE write
      if (lane == 0) {
        s_row4col[j1] = (short)r;
        s_col4row[r] = (short)j1;
        if (old >= 0) { s_col4row[old] = -1; s_q[tail & QMASK] = (short)old; }
      }
      if (old >= 0) ++tail;
      __threadfence_block();
    }
    // safety fallback (unreachable in practice)
    if (lane == 0 && head < tail) {
      for (int i = 0; i < MTARG; ++i) {
        if (s_col4row[i] < 0) {
          for (int j = 0; j < K; ++j) {
            if (s_row4col[j] < 0) { s_row4col[j] = (short)i; s_col4row[i] = (short)j; break; }
          }
        }
      }
    }
  }
  __syncthreads();

  // ---------- phase 6: loss = sum matched full costs - sum lca ----------
  float acc;
  {
    const int j = (int)s_col4row[tid];
    const float4 q = s_k4[j];
    const float4 m2 = s_m2t[tid];
    acc = s_rc[tid] + s_cc[j]
        + m2.x*q.x + m2.y*q.y + m2.z*q.z + m2.w*q.w;
  }
#pragma unroll
  for (int off = 32; off > 0; off >>= 1) acc += __shfl_down(acc, off);
  __syncthreads();
  if ((tid & 63) == 0) s_scr[tid >> 6] = acc;
  __syncthreads();
  if (tid == 0) {
    float s = 0.0f;
    for (int w = 0; w < NW; ++w) s += s_scr[w];
    out[0] = s - s_sumlca;
  }
}

extern "C" void kernel_launch(void* const* d_in, const int* in_sizes, int n_in,
                              void* d_out, int out_size, void* d_ws, size_t ws_size,
                              hipStream_t stream) {
  const float* pred  = (const float*)d_in[0];
  const float* label = (const float*)d_in[1];
  float* out = (float*)d_out;
  hipLaunchKernelGGL(lap_loss_kernel, dim3(1), dim3(NT), 0, stream,
                     pred, label, out);
}